// Round 2
// baseline (699.008 us; speedup 1.0000x reference)
//
#include <hip/hip_runtime.h>

// snnTorch Leaky recurrence, reset_mechanism='subtract':
//   reset_t = H(mem_{t-1} - uth) == spk_{t-1}
//   mem_t   = beta*mem_{t-1} + x_t - reset_t*uth
//   spk_t   = H(mem_t - uth)
// N=8192 independent chains, T=4000 sequential.
//
// R1 lesson: per-lane row streaming = 64 divergent addresses per vmem instr
// -> ~64 cyc address processing each -> txn-rate bound at 850 GB/s (10% peak).
// R2: coalesce via LDS. Wave loads ONE row's 1KB segment per instruction
// (fully coalesced), tiles 64 neurons x 256 timesteps into 64KB LDS with an
// XOR swizzle (col^row) so both staging (row-major) and compute (col-major)
// directions are bank-conflict-free for b128 ops. Compute in-place, stage out
// coalesced.
//
// Numerics: exact reference rounding order ((0.95*mem + x) - r), no fma
// contraction (__f*_rn) — a 1-ulp diff near threshold flips a spike (R0/R1
// verified: absmax 0.0 with this ordering).

namespace {

constexpr int T_LEN  = 4000;
constexpr int N_NEU  = 8192;
constexpr int ROWS   = 64;                   // neurons per block (= 1 wave)
constexpr int TT     = 256;                  // timesteps per tile
constexpr int CT     = TT / 4;               // 64 float4 columns per row
constexpr int FULLT  = T_LEN / TT;           // 15 full tiles
constexpr int TAIL_C = (T_LEN - FULLT * TT) / 4;  // 40 float4 cols in tail

__device__ __forceinline__ float step1(float x, float& mem, float& r) {
    float t = __fmul_rn(0.95f, mem);
    t       = __fadd_rn(t, x);
    mem     = __fsub_rn(t, r);
    r = (mem > 1.0f) ? 1.0f : 0.0f;   // spike_t == reset_{t+1}
    return r;
}

__device__ __forceinline__ void step4(float4 v, float4& s, float& mem, float& r) {
    s.x = step1(v.x, mem, r);
    s.y = step1(v.y, mem, r);
    s.z = step1(v.z, mem, r);
    s.w = step1(v.w, mem, r);
}

// One tile: stage in (coalesced), compute (per-lane row), stage out (coalesced).
// C = float4 columns in this tile (64 full / 40 tail), compile-time.
template <int C>
__device__ __forceinline__ void do_tile(const float* __restrict__ xrow0,
                                        float* __restrict__ orow0,
                                        float4* __restrict__ buf,
                                        int l, float& mem, float& r) {
    // ---- stage in: lane l handles float4-column l of every row ----
    if (l < C) {
        const float* src = xrow0 + l * 4;
#pragma unroll
        for (int rg = 0; rg < ROWS; rg += 8) {
            float4 v[8];
#pragma unroll
            for (int k = 0; k < 8; ++k)
                v[k] = *reinterpret_cast<const float4*>(src + (size_t)(rg + k) * T_LEN);
#pragma unroll
            for (int k = 0; k < 8; ++k)
                buf[(rg + k) * CT + (l ^ (rg + k))] = v[k];   // XOR swizzle
        }
    }
    __syncthreads();

    // ---- compute: lane l owns neuron row l ----
    {
        float4* row = buf + l * CT;
#pragma unroll 8
        for (int c = 0; c < C; ++c) {
            float4 v = row[c ^ l];
            float4 s;
            step4(v, s, mem, r);
            row[c ^ l] = s;            // overwrite input with spikes in-place
        }
    }
    __syncthreads();

    // ---- stage out: coalesced ----
    if (l < C) {
        float* dst = orow0 + l * 4;
#pragma unroll
        for (int rg = 0; rg < ROWS; rg += 8) {
            float4 v[8];
#pragma unroll
            for (int k = 0; k < 8; ++k)
                v[k] = buf[(rg + k) * CT + (l ^ (rg + k))];
#pragma unroll
            for (int k = 0; k < 8; ++k)
                *reinterpret_cast<float4*>(dst + (size_t)(rg + k) * T_LEN) = v[k];
        }
    }
    __syncthreads();
}

__global__ __launch_bounds__(64, 1)
void snn_leaky(const float* __restrict__ x, float* __restrict__ out) {
    __shared__ float4 buf[ROWS * CT];          // 64 KB, XOR-swizzled tile
    const int l  = threadIdx.x;                // lane (block = 1 wave)
    const size_t n0 = (size_t)blockIdx.x * ROWS;

    float mem = 0.0f;   // mem_0 = 0
    float r   = 0.0f;   // reset_1 = H(0-1) = 0

    const float* xbase = x   + n0 * T_LEN;
    float*       obase = out + n0 * T_LEN;

    for (int tile = 0; tile < FULLT; ++tile)
        do_tile<CT>(xbase + tile * TT, obase + tile * TT, buf, l, mem, r);
    do_tile<TAIL_C>(xbase + FULLT * TT, obase + FULLT * TT, buf, l, mem, r);
}

} // namespace

extern "C" void kernel_launch(void* const* d_in, const int* in_sizes, int n_in,
                              void* d_out, int out_size, void* d_ws, size_t ws_size,
                              hipStream_t stream) {
    const float* x = (const float*)d_in[0];
    float* out     = (float*)d_out;
    // 128 blocks x 64 threads: one wave per block, 64 neurons per wave.
    snn_leaky<<<dim3(N_NEU / ROWS), dim3(ROWS), 0, stream>>>(x, out);
}

// Round 3
// 302.489 us; speedup vs baseline: 2.3109x; 2.3109x over previous
//
#include <hip/hip_runtime.h>

// snnTorch Leaky recurrence, reset='subtract':
//   mem_t = 0.95*mem_{t-1} + x_t - spk_{t-1};  spk_t = (mem_t > 1)
// N=8192 independent chains (hard cap: 128 waves), T=4000 sequential.
//
// R1: per-lane divergent streams -> txn/latency bound, 154 us.
// R2: LDS tiling + __syncthreads + VGPR-staged loads -> compiler serialized
//     loads 1-deep (VALUBusy 0.8%), 546 us.
// R3: single wave per block, NO barriers. Stage-in via async
//     global_load_lds (16B): 64 row-loads per tile all in flight, one
//     latency per tile. Separate in/out LDS buffers so tile t+1's loads are
//     issued before tile t's stage-out stores (latency hidden behind them).
//     Tile = 200 steps -> 20 uniform tiles, no tail.
//
// LDS layout: row r at float4 offset r*65 (stride 65*16=1040 B >= 1024 B
// landing span; stride = 260 dwords = 4 mod 32 -> lane-row b128 reads hit 8
// distinct bank-groups per 8-lane phase = conflict-free, same structure R2
// measured at SQ_LDS_BANK_CONFLICT=0).
//
// Numerics: exact reference rounding ((0.95*mem + x) - r) via __f*_rn, no
// fma contraction — verified absmax 0.0 in R1/R2.

namespace {

constexpr int T_LEN = 4000;
constexpr int N_NEU = 8192;
constexpr int ROWS  = 64;          // neurons per block = lanes per wave
constexpr int TT    = 200;         // timesteps per tile
constexpr int CT    = TT / 4;      // 50 float4 columns per row-tile
constexpr int NT    = T_LEN / TT;  // 20 tiles
constexpr int RS    = 65;          // LDS row stride in float4

__device__ __forceinline__ float step1(float x, float& mem, float& r) {
    float t = __fmul_rn(0.95f, mem);
    t       = __fadd_rn(t, x);
    mem     = __fsub_rn(t, r);
    r = (mem > 1.0f) ? 1.0f : 0.0f;   // spike_t == reset_{t+1}
    return r;
}

__device__ __forceinline__ void stage_in_async(const float* src_row0,
                                               float4* ibuf) {
    // One instruction per row: 64 lanes x 16B = 1KB coalesced, lands at
    // lds_base + lane*16. All 64 loads fire-and-forget (single vmcnt wait
    // later) — this is the MLP fix for R2's serialization.
#pragma unroll
    for (int rr = 0; rr < ROWS; ++rr) {
        __builtin_amdgcn_global_load_lds(
            (const __attribute__((address_space(1))) void*)(src_row0 + (size_t)rr * T_LEN),
            (__attribute__((address_space(3))) void*)&ibuf[rr * RS],
            16, 0, 0);
    }
}

__global__ __launch_bounds__(64, 1)
void snn_leaky(const float* __restrict__ x, float* __restrict__ out) {
    __shared__ float4 ibuf[ROWS * RS];   // 66560 B
    __shared__ float4 obuf[ROWS * RS];   // 66560 B (total 133120 < 160K)

    const int l = threadIdx.x;
    const size_t n0 = (size_t)blockIdx.x * ROWS;
    const float* xb = x + n0 * T_LEN;
    float*       ob = out + n0 * T_LEN;

    // Clamp lanes >= CT to a valid column: duplicate global reads (L1-merged),
    // LDS landing stays inside this row's 1040B slot. Branch-free and no OOB.
    const int lc = (l < CT) ? l : (CT - 1);

    float mem = 0.0f;   // mem_0 = 0
    float r   = 0.0f;   // reset_1 = H(0-1) = 0

    stage_in_async(xb + lc * 4, ibuf);   // prefetch tile 0

    for (int t = 0; t < NT; ++t) {
        // ---- compute tile t: lane l owns neuron row l ----
        // (compiler inserts the vmcnt wait before the first ds_read)
        {
            const float4* irow = ibuf + l * RS;
            float4*       orow = obuf + l * RS;
#pragma unroll 10
            for (int c = 0; c < CT; ++c) {
                float4 v = irow[c], s;
                s.x = step1(v.x, mem, r);
                s.y = step1(v.y, mem, r);
                s.z = step1(v.z, mem, r);
                s.w = step1(v.w, mem, r);
                orow[c] = s;
            }
        }

        // ---- issue async loads for tile t+1 (ibuf fully consumed above;
        //      single wave -> no barrier; overlaps with stage-out below) ----
        if (t + 1 < NT)
            stage_in_async(xb + (t + 1) * TT + lc * 4, ibuf);

        // ---- stage-out tile t: coalesced 1KB stores, fire-and-forget ----
        if (l < CT) {
            float* dst = ob + t * TT + l * 4;
#pragma unroll 8
            for (int rr = 0; rr < ROWS; ++rr) {
                float4 v = obuf[rr * RS + l];
                *reinterpret_cast<float4*>(dst + (size_t)rr * T_LEN) = v;
            }
        }
    }
}

} // namespace

extern "C" void kernel_launch(void* const* d_in, const int* in_sizes, int n_in,
                              void* d_out, int out_size, void* d_ws, size_t ws_size,
                              hipStream_t stream) {
    const float* x = (const float*)d_in[0];
    float* out     = (float*)d_out;
    // 128 blocks x 1 wave: 64 neurons per wave (parallelism cap = 128 waves).
    snn_leaky<<<dim3(N_NEU / ROWS), dim3(ROWS), 0, stream>>>(x, out);
}

// Round 4
// 291.123 us; speedup vs baseline: 2.4011x; 1.0390x over previous
//
#include <hip/hip_runtime.h>

// snnTorch Leaky recurrence, reset='subtract':
//   mem_t = 0.95*mem_{t-1} + x_t - spk_{t-1};  spk_t = (mem_t > 1)
// N=8192 independent chains (cap: 128 waves), T=4000 sequential.
//
// R3 post-mortem: per-wave serialized tile round trips (~17.6K cyc/tile) —
// no double-buffer + waits forced to vmcnt(0) because 64 loads + 64 stores
// outstanding exceeds the encodable vmcnt max (63).
// R4: (1) bit-pack spikes (write 4 MB not 131 MB; no output LDS staging; a
// separate massively-parallel expand kernel writes the float output at full
// chip BW); (2) two distinct LDS buffers with prefetch issued in 32-load
// halves around each compute, so every wait point has exactly 32-34 newer
// vmem ops -> compiler can emit precise vmcnt(32) and keep the next tile's
// loads in flight across compute.
//
// Numerics: exact reference rounding ((0.95*mem + x) - r) via __f*_rn, no
// fma contraction — verified absmax 0.0 in R1-R3. Spike bit uses the same
// (mem > 1.0f) predicate as r (compiler reuses the v_cmp).

namespace {

constexpr int T_LEN = 4000;
constexpr int N_NEU = 8192;
constexpr int ROWS  = 64;               // neurons per block = lanes per wave
constexpr int TT    = 256;              // steps per full tile (row = 1024 B = 1 landing)
constexpr int CT    = TT / 4;           // 64 float4 per row
constexpr int NFT   = 15;               // full tiles
constexpr int TAILT = T_LEN - NFT * TT; // 160
constexpr int TAILC = TAILT / 4;        // 40 float4
constexpr int RS    = 65;               // LDS row stride (float4): 1040 B >= 1024 landing,
                                        // bank-conflict-free lane-row reads (R2/R3: 0 conflicts)
constexpr int QROW  = 128;              // packed row stride in u32 (125 used, padded for 16B align)
constexpr size_t QBYTES = (size_t)N_NEU * QROW * 4;  // 4 MiB scratch

__device__ __forceinline__ unsigned step1(float x, float& mem, float& r) {
    float t = __fmul_rn(0.95f, mem);
    t       = __fadd_rn(t, x);
    mem     = __fsub_rn(t, r);
    bool s  = mem > 1.0f;
    r = s ? 1.0f : 0.0f;      // spike_t == reset_{t+1}
    return s ? 1u : 0u;
}

// Async-load rows [r0, r0+32) of full tile `tile` into buf (1 KB coalesced
// per instruction, direct to LDS, fire-and-forget).
__device__ __forceinline__ void load_half(const float* __restrict__ xb, int tile,
                                          float4* buf, int r0, int l) {
    const float* src = xb + tile * TT + (size_t)r0 * T_LEN + l * 4;
#pragma unroll
    for (int k = 0; k < 32; ++k)
        __builtin_amdgcn_global_load_lds(
            (const __attribute__((address_space(1))) void*)(src + (size_t)k * T_LEN),
            (__attribute__((address_space(3))) void*)&buf[(r0 + k) * RS], 16, 0, 0);
}

// Tail tile (160 steps = 640 B/row): lanes >= 40 clamp to col 39 (duplicate
// global reads; LDS landing stays inside the 1040 B row slot).
__device__ __forceinline__ void load_tail_half(const float* __restrict__ xb,
                                               float4* buf, int r0, int l) {
    const int lc = (l < TAILC) ? l : (TAILC - 1);
    const float* src = xb + NFT * TT + (size_t)r0 * T_LEN + lc * 4;
#pragma unroll
    for (int k = 0; k < 32; ++k)
        __builtin_amdgcn_global_load_lds(
            (const __attribute__((address_space(1))) void*)(src + (size_t)k * T_LEN),
            (__attribute__((address_space(3))) void*)&buf[(r0 + k) * RS], 16, 0, 0);
}

// Compute C float4-steps from buf, packing spike bits 4/nibble into u32s;
// store W=C/8 words (32 B for full tile) to this lane's packed row.
template <int C, int W>
__device__ __forceinline__ void compute_tile(const float4* buf, int l,
                                             float& mem, float& r,
                                             unsigned* __restrict__ qrow) {
    const float4* irow = buf + l * RS;
    unsigned u[W];
#pragma unroll
    for (int w = 0; w < W; ++w) u[w] = 0;
#pragma unroll
    for (int c = 0; c < C; ++c) {
        float4 v = irow[c];
        unsigned b;
        b  = step1(v.x, mem, r);
        b |= step1(v.y, mem, r) << 1;
        b |= step1(v.z, mem, r) << 2;
        b |= step1(v.w, mem, r) << 3;
        u[c >> 3] |= b << ((c & 7) * 4);
    }
    if (W == 8) {
        uint4 a = make_uint4(u[0], u[1], u[2], u[3]);
        uint4 bq = make_uint4(u[4], u[5], u[6], u[7]);
        *reinterpret_cast<uint4*>(qrow)     = a;
        *reinterpret_cast<uint4*>(qrow + 4) = bq;
    } else {  // W == 5 (tail)
        uint4 a = make_uint4(u[0], u[1], u[2], u[3]);
        *reinterpret_cast<uint4*>(qrow) = a;
        qrow[4] = u[4];
    }
}

__global__ __launch_bounds__(64, 1)
void snn_scan(const float* __restrict__ x, unsigned* __restrict__ q) {
    __shared__ float4 bufA[ROWS * RS];   // 66560 B
    __shared__ float4 bufB[ROWS * RS];   // 66560 B (133120 total < 160K)
    const int l = threadIdx.x;
    const size_t n0 = (size_t)blockIdx.x * ROWS;
    const float* xb = x + n0 * T_LEN;
    unsigned* qn = q + (n0 + l) * QROW;  // this lane's packed spike row

    float mem = 0.0f;   // mem_0 = 0
    float r   = 0.0f;   // reset_1 = H(0-1) = 0

    load_half(xb, 0, bufA, 0,  l);
    load_half(xb, 0, bufA, 32, l);

    int t = 0;
#pragma unroll 1
    for (int d = 0; d < 7; ++d) {
        load_half(xb, t + 1, bufB, 0,  l);                   // 32 newer at next wait
        compute_tile<CT, 8>(bufA, l, mem, r, qn + t * 8);    // waits vmcnt(32)
        load_half(xb, t + 1, bufB, 32, l);
        load_half(xb, t + 2, bufA, 0,  l);
        compute_tile<CT, 8>(bufB, l, mem, r, qn + (t + 1) * 8);
        load_half(xb, t + 2, bufA, 32, l);
        t += 2;
    }
    // t == 14; bufA holds tile 14 (loaded across the last round).
    load_tail_half(xb, bufB, 0,  l);
    compute_tile<CT, 8>(bufA, l, mem, r, qn + 14 * 8);
    load_tail_half(xb, bufB, 32, l);
    compute_tile<TAILC, 5>(bufB, l, mem, r, qn + 15 * 8);    // words 120..124
}

// Expand packed bits -> float spikes, fully coalesced float4 writes.
// 8192*1000 float4s = 32000 blocks x 256 threads exactly.
__global__ __launch_bounds__(256)
void snn_expand(const unsigned* __restrict__ q, float* __restrict__ out) {
    const unsigned i = blockIdx.x * 256 + threadIdx.x;  // float4 index
    const unsigned n = i / 1000u;                       // neuron row (magic mul)
    const unsigned c = i - n * 1000u;                   // float4 col
    const unsigned w = q[n * QROW + (c >> 3)];
    const unsigned nib = w >> ((c & 7u) * 4u);
    float4 f;
    f.x = (nib & 1u) ? 1.0f : 0.0f;
    f.y = (nib & 2u) ? 1.0f : 0.0f;
    f.z = (nib & 4u) ? 1.0f : 0.0f;
    f.w = (nib & 8u) ? 1.0f : 0.0f;
    reinterpret_cast<float4*>(out)[i] = f;
}

// ---------------- fallback (R3, known-passing) if ws_size < 4 MiB ----------
constexpr int FTT = 200, FCT = FTT / 4, FNT = T_LEN / FTT;

__device__ __forceinline__ float fstep(float x, float& mem, float& r) {
    float t = __fmul_rn(0.95f, mem);
    t       = __fadd_rn(t, x);
    mem     = __fsub_rn(t, r);
    r = (mem > 1.0f) ? 1.0f : 0.0f;
    return r;
}

__device__ __forceinline__ void fstage(const float* src_row0, float4* ibuf) {
#pragma unroll
    for (int rr = 0; rr < ROWS; ++rr)
        __builtin_amdgcn_global_load_lds(
            (const __attribute__((address_space(1))) void*)(src_row0 + (size_t)rr * T_LEN),
            (__attribute__((address_space(3))) void*)&ibuf[rr * RS], 16, 0, 0);
}

__global__ __launch_bounds__(64, 1)
void snn_leaky_fb(const float* __restrict__ x, float* __restrict__ out) {
    __shared__ float4 ibuf[ROWS * RS];
    __shared__ float4 obuf[ROWS * RS];
    const int l = threadIdx.x;
    const size_t n0 = (size_t)blockIdx.x * ROWS;
    const float* xb = x + n0 * T_LEN;
    float*       ob = out + n0 * T_LEN;
    const int lc = (l < FCT) ? l : (FCT - 1);
    float mem = 0.0f, r = 0.0f;
    fstage(xb + lc * 4, ibuf);
    for (int t = 0; t < FNT; ++t) {
        {
            const float4* irow = ibuf + l * RS;
            float4*       orow = obuf + l * RS;
#pragma unroll 10
            for (int c = 0; c < FCT; ++c) {
                float4 v = irow[c], s;
                s.x = fstep(v.x, mem, r);
                s.y = fstep(v.y, mem, r);
                s.z = fstep(v.z, mem, r);
                s.w = fstep(v.w, mem, r);
                orow[c] = s;
            }
        }
        if (t + 1 < FNT) fstage(xb + (t + 1) * FTT + lc * 4, ibuf);
        if (l < FCT) {
            float* dst = ob + t * FTT + l * 4;
#pragma unroll 8
            for (int rr = 0; rr < ROWS; ++rr) {
                float4 v = obuf[rr * RS + l];
                *reinterpret_cast<float4*>(dst + (size_t)rr * T_LEN) = v;
            }
        }
    }
}

} // namespace

extern "C" void kernel_launch(void* const* d_in, const int* in_sizes, int n_in,
                              void* d_out, int out_size, void* d_ws, size_t ws_size,
                              hipStream_t stream) {
    const float* x = (const float*)d_in[0];
    float* out     = (float*)d_out;
    if (ws_size >= QBYTES) {
        unsigned* q = (unsigned*)d_ws;
        snn_scan<<<dim3(N_NEU / ROWS), dim3(64), 0, stream>>>(x, q);
        snn_expand<<<dim3(32000), dim3(256), 0, stream>>>(q, out);
    } else {
        // scratch too small for packed spikes: known-passing R3 path
        snn_leaky_fb<<<dim3(N_NEU / ROWS), dim3(64), 0, stream>>>(x, out);
    }
}